// Round 5
// baseline (164.655 us; speedup 1.0000x reference)
//
#include <hip/hip_runtime.h>

// VectorQuantizer gfx950 R5: split into (prep) + (argmin over codebook quarters,
// merged via packed-key atomicMin) + (streaming gather/loss).
// dist2[n,k] = ||x||^2 - 2 x.e_k + ||e_k||^2 ; argmin invariant to ||x||^2.
// A-fragments hold bf16(-2x) (exact pow2 scale); MFMA C-operand initialized to
// cc = 0.5 + ||e_k||^2 so the MFMA output IS the score s in ~[0.31,0.69] (>0 =>
// IEEE bits order-monotonic). key = (bits(s) & ~1023) | code; global argmin =
// atomicMin on u32 keys. Ties pick lowest code, matching jnp.argmin.
// vq_argmin: 36 KB LDS (256 codes, stride 68 => only the inherent 8/bank b128
// aliasing) -> 4 blocks/CU co-resident, 16 waves/CU, 2048 blocks for balance.

typedef __attribute__((ext_vector_type(8))) short short8;
typedef __attribute__((ext_vector_type(4))) float f32x4;

#define VQ_D 64
#define CSTRIDE 68  // ushorts per code row in LDS (64 data + 4 pad)

__device__ inline unsigned short f2bf(float f) {
  union { float f; unsigned u; } v; v.f = f;
  unsigned r = v.u + 0x7FFFu + ((v.u >> 16) & 1u);  // RNE
  return (unsigned short)(r >> 16);
}

// Prep: one wave per codebook row -> bf16 codebook + c2b[k]=0.5+||e_k||^2.
// Also inits keys to 0xFFFFFFFF and zeroes sse/counter. Grid 256x256 (K=1024).
__global__ __launch_bounds__(256) void vq_prep(const float* __restrict__ cb,
                                               float* __restrict__ c2b,
                                               unsigned short* __restrict__ cbb,
                                               unsigned* __restrict__ keys,
                                               float* __restrict__ sse,
                                               unsigned* __restrict__ counter) {
  int g = blockIdx.x * 256 + threadIdx.x;
  if (g == 0) { *sse = 0.f; *counter = 0u; }
  keys[g] = 0xFFFFFFFFu;
  keys[g + 65536] = 0xFFFFFFFFu;
  int w = g >> 6;
  int lane = g & 63;
  float v = cb[(size_t)w * VQ_D + lane];
  cbb[(size_t)w * VQ_D + lane] = f2bf(v);
  float s = v * v;
#pragma unroll
  for (int off = 32; off; off >>= 1) s += __shfl_down(s, off);
  if (lane == 0) c2b[w] = s + 0.5f;
}

// Argmin: block = 256 threads (4 waves x 64 rows = 256 rows) x 256 codes.
// blockIdx: quarter = b & 3, rowTile = b >> 2.
__global__ __launch_bounds__(256) void vq_argmin(
    const float* __restrict__ x, const float* __restrict__ c2b,
    const unsigned short* __restrict__ cbb, unsigned* __restrict__ keys) {
  __shared__ unsigned short cbs[256 * CSTRIDE];  // 34816 B
  __shared__ float c2s[256];                     // 1024 B
  __shared__ unsigned keybuf[256];               // 1024 B

  const int tid = threadIdx.x;
  const int wave = tid >> 6;
  const int lane = tid & 63;
  const int quad = lane >> 4;
  const int col = lane & 15;
  const int quarter = blockIdx.x & 3;
  const long rowTile0 = (long)(blockIdx.x >> 2) * 256;
  const int waveRow0 = wave * 64;

  // ---- Stage this quarter: 256 codes (32 KB) as coalesced 16B chunks.
  const unsigned short* src = cbb + (size_t)quarter * 256 * VQ_D;
#pragma unroll
  for (int r = 0; r < 8; ++r) {
    int id = r * 256 + tid;  // chunk id: code = id>>3, piece = id&7
    int code = id >> 3;
    int piece = id & 7;
    short8 v = *(const short8*)(src + code * VQ_D + piece * 8);
    *(short8*)(cbs + code * CSTRIDE + piece * 8) = v;
  }
  c2s[tid] = c2b[quarter * 256 + tid];

  // ---- A fragments: bf16(-2*x). A[m=lane&15][k=quad*8+j], rows mi*16+col.
  short8 Af[4][2];
#pragma unroll
  for (int mi = 0; mi < 4; ++mi) {
#pragma unroll
    for (int ks = 0; ks < 2; ++ks) {
      long row = rowTile0 + waveRow0 + mi * 16 + col;
      const f32x4* xp = (const f32x4*)(x + row * VQ_D + ks * 32 + quad * 8);
      f32x4 lo = xp[0];
      f32x4 hi = xp[1];
      short8 a;
      a[0] = (short)f2bf(-2.f * lo[0]); a[1] = (short)f2bf(-2.f * lo[1]);
      a[2] = (short)f2bf(-2.f * lo[2]); a[3] = (short)f2bf(-2.f * lo[3]);
      a[4] = (short)f2bf(-2.f * hi[0]); a[5] = (short)f2bf(-2.f * hi[1]);
      a[6] = (short)f2bf(-2.f * hi[2]); a[7] = (short)f2bf(-2.f * hi[3]);
      Af[mi][ks] = a;
    }
  }

  unsigned bk[4][4];
#pragma unroll
  for (int mi = 0; mi < 4; ++mi)
#pragma unroll
    for (int r = 0; r < 4; ++r) bk[mi][r] = 0xFFFFFFFFu;

  __syncthreads();

  // ---- K-loop: 16 iters x 16 codes. LDS offsets are compile-time immediates.
  const unsigned short* bbase = cbs + (size_t)col * CSTRIDE + quad * 8;
  const unsigned cbase = (unsigned)(quarter << 8) | (unsigned)col;
#pragma unroll 4
  for (int t = 0; t < 16; ++t) {
    const unsigned short* bp = bbase + t * 16 * CSTRIDE;
    short8 b0 = *(const short8*)bp;
    short8 b1 = *(const short8*)(bp + 32);
    float cc = c2s[t * 16 + col];

    f32x4 acc[4];
#pragma unroll
    for (int mi = 0; mi < 4; ++mi) {
      f32x4 a = {cc, cc, cc, cc};
      a = __builtin_amdgcn_mfma_f32_16x16x32_bf16(Af[mi][0], b0, a, 0, 0, 0);
      a = __builtin_amdgcn_mfma_f32_16x16x32_bf16(Af[mi][1], b1, a, 0, 0, 0);
      acc[mi] = a;
    }

    const unsigned code = cbase | (unsigned)(t << 4);
#pragma unroll
    for (int mi = 0; mi < 4; ++mi)
#pragma unroll
      for (int r = 0; r < 4; ++r)
        bk[mi][r] = min(bk[mi][r], (__float_as_uint(acc[mi][r]) & 0xFFFFFC00u) | code);
  }

  // ---- Reduce keys across the 16 columns of each quad group.
#pragma unroll
  for (int off = 1; off < 16; off <<= 1) {
#pragma unroll
    for (int mi = 0; mi < 4; ++mi)
#pragma unroll
      for (int r = 0; r < 4; ++r) {
        unsigned o = (unsigned)__shfl_xor((int)bk[mi][r], off);
        bk[mi][r] = min(bk[mi][r], o);
      }
  }
  if (col == 0) {
#pragma unroll
    for (int mi = 0; mi < 4; ++mi)
#pragma unroll
      for (int r = 0; r < 4; ++r)
        keybuf[waveRow0 + mi * 16 + quad * 4 + r] = bk[mi][r];
  }
  __syncthreads();

  // One coalesced device-scope atomicMin per row: merges the 4 quarters.
  atomicMin(&keys[rowTile0 + tid], keybuf[tid]);
}

// Gather + loss: pure streaming, high occupancy. 1024 blocks x 256 thr x 8 f32x4.
__global__ __launch_bounds__(256) void vq_gather(
    const float* __restrict__ x, const float* __restrict__ cb,
    const unsigned* __restrict__ keys, float* __restrict__ out,
    float* __restrict__ sse_out, unsigned* __restrict__ counter,
    long nelem, int nblocks) {
  __shared__ float redbuf[4];
  const int tid = threadIdx.x;
  const f32x4* cb4 = (const f32x4*)cb;
  const f32x4* x4 = (const f32x4*)x;
  f32x4* out4 = (f32x4*)out;

  float sse = 0.f;
#pragma unroll
  for (int i = 0; i < 8; ++i) {
    int f = blockIdx.x * 2048 + i * 256 + tid;  // contiguous float4 index
    int row = f >> 4;
    int d4 = f & 15;
    unsigned idx = keys[row] & 1023u;
    f32x4 cv = cb4[(size_t)idx * 16 + d4];
    f32x4 xv = x4[f];
    out4[f] = cv;
    f32x4 dv = cv - xv;
    sse += dv[0] * dv[0] + dv[1] * dv[1] + dv[2] * dv[2] + dv[3] * dv[3];
  }
#pragma unroll
  for (int off = 32; off; off >>= 1) sse += __shfl_down(sse, off);
  if ((tid & 63) == 0) redbuf[tid >> 6] = sse;
  __syncthreads();
  if (tid == 0) {
    atomicAdd(sse_out, redbuf[0] + redbuf[1] + redbuf[2] + redbuf[3]);
    __threadfence();
    unsigned old = atomicAdd(counter, 1u);
    if (old == (unsigned)(nblocks - 1)) {
      float tot = atomicAdd(sse_out, 0.f);
      out[nelem] = 1.25f * tot / (float)nelem;
    }
  }
}

extern "C" void kernel_launch(void* const* d_in, const int* in_sizes, int n_in,
                              void* d_out, int out_size, void* d_ws, size_t ws_size,
                              hipStream_t stream) {
  const float* x = (const float*)d_in[0];
  const float* cb = (const float*)d_in[1];
  float* out = (float*)d_out;

  const long n_elem = (long)in_sizes[0];   // 8388608
  const int nrows = (int)(n_elem / VQ_D);  // 131072

  char* ws = (char*)d_ws;
  float* sse = (float*)ws;                             // 4 B
  unsigned* counter = (unsigned*)(ws + 64);            // 4 B
  float* c2b = (float*)(ws + 256);                     // 4 KB
  unsigned short* cbb = (unsigned short*)(ws + 8192);  // 128 KB bf16 codebook
  unsigned* keys = (unsigned*)(ws + 139264);           // 512 KB packed keys

  const int gather_blocks = nrows / 128;  // 1024, each covers 128 rows (2048 f32x4)

  vq_prep<<<dim3(256), dim3(256), 0, stream>>>(cb, c2b, cbb, keys, sse, counter);
  vq_argmin<<<dim3((nrows / 256) * 4), dim3(256), 0, stream>>>(x, c2b, cbb, keys);
  vq_gather<<<dim3(gather_blocks), dim3(256), 0, stream>>>(
      x, cb, keys, out, sse, counter, n_elem, gather_blocks);
}

// Round 6
// 155.804 us; speedup vs baseline: 1.0568x; 1.0568x over previous
//
#include <hip/hip_runtime.h>

// VectorQuantizer gfx950 R6: ONE fused kernel. Full bf16 codebook in LDS
// (staged straight from fp32, converted in-kernel), c2 via 8-lane shuffle
// during staging, bf16-MFMA K-loop with packed-key argmin, per-wave epilogue
// that gathers the output rows FROM LDS (bf16->fp32) and computes the loss
// analytically: SSE_row = ||x||^2_fp32 + (s_win - 0.5), no x re-read.
// dist2[n,k] = ||x||^2 - 2 x.e_k + ||e_k||^2 ; argmin invariant to ||x||^2.
// A-frags hold bf16(-2x) (exact pow2 scale); MFMA C init = cc = 0.5+||e_k||^2
// so the MFMA output IS s in ~[0.31,0.69] (>0 => IEEE bits order-monotonic).
// key = (bits(s) & ~1023) | code ; argmin = v_min_u32 ; ties -> lowest code.
// Grid 256 x 1024 threads: 16 waves/CU (4/SIMD), LDS 145.5 KB -> 1 block/CU.

typedef __attribute__((ext_vector_type(8))) short short8;
typedef __attribute__((ext_vector_type(4))) float f32x4;

#define VQ_D 64
#define CSTRIDE 68       // ushorts per code row in LDS (64 data + 4 pad) — measured 0 conflicts
#define ROWS_PER_BLOCK 512

__device__ inline unsigned short f2bf(float f) {
  union { float f; unsigned u; } v; v.f = f;
  unsigned r = v.u + 0x7FFFu + ((v.u >> 16) & 1u);  // RNE
  return (unsigned short)(r >> 16);
}

__global__ __launch_bounds__(1024) void vq_fused(
    const float* __restrict__ x, const float* __restrict__ cb,
    float* __restrict__ out, float* __restrict__ sse_out,
    unsigned* __restrict__ counter, int nblocks) {
  __shared__ unsigned short cbs[1024 * CSTRIDE];  // 139264 B
  __shared__ float c2s[1024];                     // 4096 B
  __shared__ int idxs[ROWS_PER_BLOCK];            // 2048 B
  __shared__ float redbuf[16];

  const int tid = threadIdx.x;   // 0..1023
  const int wave = tid >> 6;     // 0..15
  const int lane = tid & 63;
  const int quad = lane >> 4;
  const int col = lane & 15;
  const long blockRow0 = (long)blockIdx.x * ROWS_PER_BLOCK;
  const int waveRow0 = wave * 32;

  // ---- (a) Stage codebook fp32 -> bf16 -> LDS, and fold the c2 computation
  // into the same pass: chunk id -> code = id>>3, piece = id&7 (8 B piece of 8
  // floats... 8 floats = 32 B global, 16 B bf16 in LDS). The 8 threads of one
  // code are consecutive lanes -> 3 xor-shuffles combine their partial sums.
#pragma unroll
  for (int r = 0; r < 8; ++r) {
    int id = r * 1024 + tid;
    int code = id >> 3;
    int piece = id & 7;
    const f32x4* sp = (const f32x4*)(cb + (size_t)code * VQ_D + piece * 8);
    f32x4 lo = sp[0];
    f32x4 hi = sp[1];
    short8 v;
    v[0] = (short)f2bf(lo[0]); v[1] = (short)f2bf(lo[1]);
    v[2] = (short)f2bf(lo[2]); v[3] = (short)f2bf(lo[3]);
    v[4] = (short)f2bf(hi[0]); v[5] = (short)f2bf(hi[1]);
    v[6] = (short)f2bf(hi[2]); v[7] = (short)f2bf(hi[3]);
    *(short8*)(cbs + code * CSTRIDE + piece * 8) = v;
    float p = lo[0] * lo[0] + lo[1] * lo[1] + lo[2] * lo[2] + lo[3] * lo[3] +
              hi[0] * hi[0] + hi[1] * hi[1] + hi[2] * hi[2] + hi[3] * hi[3];
    p += __shfl_xor(p, 1);
    p += __shfl_xor(p, 2);
    p += __shfl_xor(p, 4);
    if (piece == 0) c2s[code] = p + 0.5f;
  }

  // ---- (b) A fragments: bf16(-2x) + fp32 ||x||^2 partial for the loss.
  // A[m=lane&15][k=quad*8+j]; rows mi*16+col of this wave's 32 rows.
  short8 Af[2][2];
  float xsq = 0.f;
#pragma unroll
  for (int mi = 0; mi < 2; ++mi) {
#pragma unroll
    for (int ks = 0; ks < 2; ++ks) {
      long row = blockRow0 + waveRow0 + mi * 16 + col;
      const f32x4* xp = (const f32x4*)(x + row * VQ_D + ks * 32 + quad * 8);
      f32x4 lo = xp[0];
      f32x4 hi = xp[1];
      xsq += lo[0] * lo[0] + lo[1] * lo[1] + lo[2] * lo[2] + lo[3] * lo[3] +
             hi[0] * hi[0] + hi[1] * hi[1] + hi[2] * hi[2] + hi[3] * hi[3];
      short8 a;
      a[0] = (short)f2bf(-2.f * lo[0]); a[1] = (short)f2bf(-2.f * lo[1]);
      a[2] = (short)f2bf(-2.f * lo[2]); a[3] = (short)f2bf(-2.f * lo[3]);
      a[4] = (short)f2bf(-2.f * hi[0]); a[5] = (short)f2bf(-2.f * hi[1]);
      a[6] = (short)f2bf(-2.f * hi[2]); a[7] = (short)f2bf(-2.f * hi[3]);
      Af[mi][ks] = a;
    }
  }

  unsigned bk[2][4];
#pragma unroll
  for (int mi = 0; mi < 2; ++mi)
#pragma unroll
    for (int r = 0; r < 4; ++r) bk[mi][r] = 0xFFFFFFFFu;

  __syncthreads();  // staging + c2 complete

  // ---- (c) K-loop: 64 iters x 16 codes. LDS + MFMA + 2 VALU/score only.
  const unsigned short* bbase = cbs + (size_t)col * CSTRIDE + quad * 8;
#pragma unroll 4
  for (int t = 0; t < 64; ++t) {
    const unsigned short* bp = bbase + t * 16 * CSTRIDE;
    short8 b0 = *(const short8*)bp;
    short8 b1 = *(const short8*)(bp + 32);
    float cc = c2s[t * 16 + col];

    f32x4 a0 = {cc, cc, cc, cc};
    f32x4 a1 = {cc, cc, cc, cc};
    a0 = __builtin_amdgcn_mfma_f32_16x16x32_bf16(Af[0][0], b0, a0, 0, 0, 0);
    a0 = __builtin_amdgcn_mfma_f32_16x16x32_bf16(Af[0][1], b1, a0, 0, 0, 0);
    a1 = __builtin_amdgcn_mfma_f32_16x16x32_bf16(Af[1][0], b0, a1, 0, 0, 0);
    a1 = __builtin_amdgcn_mfma_f32_16x16x32_bf16(Af[1][1], b1, a1, 0, 0, 0);

    const unsigned code = (unsigned)((t << 4) + col);
#pragma unroll
    for (int r = 0; r < 4; ++r) {
      bk[0][r] = min(bk[0][r], (__float_as_uint(a0[r]) & 0xFFFFFC00u) | code);
      bk[1][r] = min(bk[1][r], (__float_as_uint(a1[r]) & 0xFFFFFC00u) | code);
    }
  }

  // ---- (d) Col-reduce keys (all 16 cols end up with the row minimum).
#pragma unroll
  for (int off = 1; off < 16; off <<= 1) {
#pragma unroll
    for (int mi = 0; mi < 2; ++mi)
#pragma unroll
      for (int r = 0; r < 4; ++r) {
        unsigned o = (unsigned)__shfl_xor((int)bk[mi][r], off);
        bk[mi][r] = min(bk[mi][r], o);
      }
  }

  // s_win sum for the loss (each row duplicated on 16 cols -> /16 later).
  float ssum = 0.f;
#pragma unroll
  for (int mi = 0; mi < 2; ++mi)
#pragma unroll
    for (int r = 0; r < 4; ++r)
      ssum += __uint_as_float(bk[mi][r] & 0xFFFFFC00u) - 0.5f;

  // Per-wave idxs (same-wave write->read; no block barrier needed).
  if (col == 0) {
#pragma unroll
    for (int mi = 0; mi < 2; ++mi)
#pragma unroll
      for (int r = 0; r < 4; ++r)
        idxs[waveRow0 + mi * 16 + quad * 4 + r] = (int)(bk[mi][r] & 1023u);
  }

  // ---- (e) Epilogue: gather this wave's 32 rows FROM LDS (bf16->fp32), write out.
  f32x4* out4 = (f32x4*)out;
#pragma unroll
  for (int i = 0; i < 8; ++i) {
    int c = i * 64 + lane;   // 0..511 : row_l = c>>4 (0..31), d4 = c&15
    int row_l = c >> 4;
    int d4 = c & 15;
    int idx = idxs[waveRow0 + row_l];
    const unsigned* p = (const unsigned*)(cbs + (size_t)idx * CSTRIDE + d4 * 4);
    unsigned u0 = p[0], u1 = p[1];
    f32x4 cv;
    cv[0] = __uint_as_float(u0 << 16);
    cv[1] = __uint_as_float(u0 & 0xFFFF0000u);
    cv[2] = __uint_as_float(u1 << 16);
    cv[3] = __uint_as_float(u1 & 0xFFFF0000u);
    long gi = (blockRow0 + waveRow0 + row_l) * 16 + d4;
    out4[gi] = cv;
  }

  // ---- (f) Loss: SSE = sum_rows ||x||^2 + sum_rows (s_win - 0.5).
  float part = xsq + ssum * 0.0625f;  // ssum counted 16x per row
#pragma unroll
  for (int off = 32; off; off >>= 1) part += __shfl_down(part, off);
  if (lane == 0) redbuf[wave] = part;
  __syncthreads();
  if (tid == 0) {
    float s = 0.f;
#pragma unroll
    for (int w = 0; w < 16; ++w) s += redbuf[w];
    atomicAdd(sse_out, s);
    __threadfence();
    unsigned old = atomicAdd(counter, 1u);
    if (old == (unsigned)(nblocks - 1)) {
      float tot = atomicAdd(sse_out, 0.f);
      long nelem = (long)nblocks * ROWS_PER_BLOCK * VQ_D;
      out[nelem] = 1.25f * tot / (float)nelem;
    }
  }
}

extern "C" void kernel_launch(void* const* d_in, const int* in_sizes, int n_in,
                              void* d_out, int out_size, void* d_ws, size_t ws_size,
                              hipStream_t stream) {
  const float* x = (const float*)d_in[0];
  const float* cb = (const float*)d_in[1];
  float* out = (float*)d_out;

  const long n_elem = (long)in_sizes[0];   // 8388608
  const int nrows = (int)(n_elem / VQ_D);  // 131072
  const int nblocks = nrows / ROWS_PER_BLOCK;  // 256

  float* sse = (float*)d_ws;
  unsigned* cnt = (unsigned*)((char*)d_ws + 64);

  hipMemsetAsync(d_ws, 0, 128, stream);  // zero sse + counter (graph-capturable)
  vq_fused<<<dim3(nblocks), dim3(1024), 0, stream>>>(x, cb, out, sse, cnt, nblocks);
}

// Round 7
// 132.969 us; speedup vs baseline: 1.2383x; 1.1717x over previous
//
#include <hip/hip_runtime.h>

// VectorQuantizer gfx950 R7: R4's K-loop body (512 thr, 64 rows/wave, full bf16
// codebook in LDS) + R6's epilogue (gather from LDS, analytic loss, no x re-read).
// dist2[n,k] = ||x||^2 - 2 x.e_k + ||e_k||^2 ; argmin invariant to ||x||^2.
// A-frags hold bf16(-2x) (exact pow2 scale); MFMA C init = cc = 0.5+||e_k||^2
// so the MFMA output IS s in ~[0.31,0.69] (>0 => IEEE bits order-monotonic).
// key = (bits(s) & ~1023) | code ; argmin = v_min_u32 ; ties -> lowest code.
// Loss: SSE_row = ||x||^2_fp32 + (s_win - 0.5); x is read exactly once.
// Grid 256 x 512 threads, LDS 145.5 KB -> 1 block/CU. CSTRIDE=68: measured
// 0 bank conflicts (2-way aliasing on b128 reads is free, m136).

typedef __attribute__((ext_vector_type(8))) short short8;
typedef __attribute__((ext_vector_type(4))) float f32x4;

#define VQ_D 64
#define CSTRIDE 68
#define ROWS_PER_BLOCK 512

__device__ inline unsigned short f2bf(float f) {
  union { float f; unsigned u; } v; v.f = f;
  unsigned r = v.u + 0x7FFFu + ((v.u >> 16) & 1u);  // RNE
  return (unsigned short)(r >> 16);
}

__global__ __launch_bounds__(512) void vq_fused(
    const float* __restrict__ x, const float* __restrict__ cb,
    float* __restrict__ out, float* __restrict__ sse_out,
    unsigned* __restrict__ counter, int nblocks) {
  __shared__ unsigned short cbs[1024 * CSTRIDE];  // 139264 B
  __shared__ float c2s[1024];                     // 4096 B
  __shared__ int idxs[ROWS_PER_BLOCK];            // 2048 B
  __shared__ float redbuf[8];

  const int tid = threadIdx.x;   // 0..511
  const int wave = tid >> 6;     // 0..7
  const int lane = tid & 63;
  const int quad = lane >> 4;
  const int col = lane & 15;
  const long blockRow0 = (long)blockIdx.x * ROWS_PER_BLOCK;
  const int waveRow0 = wave * 64;

  // ---- (a) Stage codebook fp32 -> bf16 -> LDS; c2 folded in via 3 xor-shuffles
  // (the 8 pieces of one code sit on 8 consecutive lanes).
#pragma unroll
  for (int r = 0; r < 16; ++r) {
    int id = r * 512 + tid;  // 0..8191 : code = id>>3, piece = id&7
    int code = id >> 3;
    int piece = id & 7;
    const f32x4* sp = (const f32x4*)(cb + (size_t)code * VQ_D + piece * 8);
    f32x4 lo = sp[0];
    f32x4 hi = sp[1];
    short8 v;
    v[0] = (short)f2bf(lo[0]); v[1] = (short)f2bf(lo[1]);
    v[2] = (short)f2bf(lo[2]); v[3] = (short)f2bf(lo[3]);
    v[4] = (short)f2bf(hi[0]); v[5] = (short)f2bf(hi[1]);
    v[6] = (short)f2bf(hi[2]); v[7] = (short)f2bf(hi[3]);
    *(short8*)(cbs + code * CSTRIDE + piece * 8) = v;
    float p = lo[0] * lo[0] + lo[1] * lo[1] + lo[2] * lo[2] + lo[3] * lo[3] +
              hi[0] * hi[0] + hi[1] * hi[1] + hi[2] * hi[2] + hi[3] * hi[3];
    p += __shfl_xor(p, 1);
    p += __shfl_xor(p, 2);
    p += __shfl_xor(p, 4);
    if (piece == 0) c2s[code] = p + 0.5f;
  }

  // ---- (b) A fragments: bf16(-2x), 64 rows/wave (mi=4); fp32 ||x||^2 partial.
  short8 Af[4][2];
  float xsq = 0.f;
#pragma unroll
  for (int mi = 0; mi < 4; ++mi) {
#pragma unroll
    for (int ks = 0; ks < 2; ++ks) {
      long row = blockRow0 + waveRow0 + mi * 16 + col;
      const f32x4* xp = (const f32x4*)(x + row * VQ_D + ks * 32 + quad * 8);
      f32x4 lo = xp[0];
      f32x4 hi = xp[1];
      xsq += lo[0] * lo[0] + lo[1] * lo[1] + lo[2] * lo[2] + lo[3] * lo[3] +
             hi[0] * hi[0] + hi[1] * hi[1] + hi[2] * hi[2] + hi[3] * hi[3];
      short8 a;
      a[0] = (short)f2bf(-2.f * lo[0]); a[1] = (short)f2bf(-2.f * lo[1]);
      a[2] = (short)f2bf(-2.f * lo[2]); a[3] = (short)f2bf(-2.f * lo[3]);
      a[4] = (short)f2bf(-2.f * hi[0]); a[5] = (short)f2bf(-2.f * hi[1]);
      a[6] = (short)f2bf(-2.f * hi[2]); a[7] = (short)f2bf(-2.f * hi[3]);
      Af[mi][ks] = a;
    }
  }

  unsigned bk[4][4];
#pragma unroll
  for (int mi = 0; mi < 4; ++mi)
#pragma unroll
    for (int r = 0; r < 4; ++r) bk[mi][r] = 0xFFFFFFFFu;

  __syncthreads();  // codebook + c2 staged; only barrier before the epilogue

  // ---- (c) K-loop: 64 iters x 16 codes (R4 body, best measured).
  const unsigned short* bbase = cbs + (size_t)col * CSTRIDE + quad * 8;
#pragma unroll 4
  for (int t = 0; t < 64; ++t) {
    const unsigned short* bp = bbase + t * 16 * CSTRIDE;
    short8 b0 = *(const short8*)bp;
    short8 b1 = *(const short8*)(bp + 32);
    float cc = c2s[t * 16 + col];

    f32x4 acc[4];
#pragma unroll
    for (int mi = 0; mi < 4; ++mi) {
      f32x4 a = {cc, cc, cc, cc};
      a = __builtin_amdgcn_mfma_f32_16x16x32_bf16(Af[mi][0], b0, a, 0, 0, 0);
      a = __builtin_amdgcn_mfma_f32_16x16x32_bf16(Af[mi][1], b1, a, 0, 0, 0);
      acc[mi] = a;
    }

    const unsigned code = (unsigned)((t << 4) + col);
#pragma unroll
    for (int mi = 0; mi < 4; ++mi)
#pragma unroll
      for (int r = 0; r < 4; ++r)
        bk[mi][r] = min(bk[mi][r], (__float_as_uint(acc[mi][r]) & 0xFFFFFC00u) | code);
  }

  // ---- (d) Col-reduce keys (all 16 cols end with the row minimum).
#pragma unroll
  for (int off = 1; off < 16; off <<= 1) {
#pragma unroll
    for (int mi = 0; mi < 4; ++mi)
#pragma unroll
      for (int r = 0; r < 4; ++r) {
        unsigned o = (unsigned)__shfl_xor((int)bk[mi][r], off);
        bk[mi][r] = min(bk[mi][r], o);
      }
  }

  // s_win sum for the loss; each row duplicated on 16 cols -> x1/16.
  float ssum = 0.f;
#pragma unroll
  for (int mi = 0; mi < 4; ++mi)
#pragma unroll
    for (int r = 0; r < 4; ++r)
      ssum += __uint_as_float(bk[mi][r] & 0xFFFFFC00u) - 0.5f;

  // Per-wave idxs (same-wave LDS write->read; no block barrier needed).
  if (col == 0) {
#pragma unroll
    for (int mi = 0; mi < 4; ++mi)
#pragma unroll
      for (int r = 0; r < 4; ++r)
        idxs[waveRow0 + mi * 16 + quad * 4 + r] = (int)(bk[mi][r] & 1023u);
  }

  // ---- (e) Epilogue: gather this wave's 64 rows FROM LDS (bf16->fp32), write out.
  f32x4* out4 = (f32x4*)out;
#pragma unroll
  for (int i = 0; i < 16; ++i) {
    int c = i * 64 + lane;   // 0..1023 : row_l = c>>4 (0..63), d4 = c&15
    int row_l = c >> 4;
    int d4 = c & 15;
    int idx = idxs[waveRow0 + row_l];
    const unsigned* p = (const unsigned*)(cbs + (size_t)idx * CSTRIDE + d4 * 4);
    unsigned u0 = p[0], u1 = p[1];
    f32x4 cv;
    cv[0] = __uint_as_float(u0 << 16);
    cv[1] = __uint_as_float(u0 & 0xFFFF0000u);
    cv[2] = __uint_as_float(u1 << 16);
    cv[3] = __uint_as_float(u1 & 0xFFFF0000u);
    long gi = (blockRow0 + waveRow0 + row_l) * 16 + d4;
    out4[gi] = cv;
  }

  // ---- (f) Loss: SSE = sum_rows ||x||^2 + sum_rows (s_win - 0.5).
  float part = xsq + ssum * 0.0625f;
#pragma unroll
  for (int off = 32; off; off >>= 1) part += __shfl_down(part, off);
  if (lane == 0) redbuf[wave] = part;
  __syncthreads();
  if (tid == 0) {
    float s = 0.f;
#pragma unroll
    for (int w = 0; w < 8; ++w) s += redbuf[w];
    atomicAdd(sse_out, s);
    __threadfence();
    unsigned old = atomicAdd(counter, 1u);
    if (old == (unsigned)(nblocks - 1)) {
      float tot = atomicAdd(sse_out, 0.f);
      long nelem = (long)nblocks * ROWS_PER_BLOCK * VQ_D;
      out[nelem] = 1.25f * tot / (float)nelem;
    }
  }
}

extern "C" void kernel_launch(void* const* d_in, const int* in_sizes, int n_in,
                              void* d_out, int out_size, void* d_ws, size_t ws_size,
                              hipStream_t stream) {
  const float* x = (const float*)d_in[0];
  const float* cb = (const float*)d_in[1];
  float* out = (float*)d_out;

  const long n_elem = (long)in_sizes[0];        // 8388608
  const int nrows = (int)(n_elem / VQ_D);       // 131072
  const int nblocks = nrows / ROWS_PER_BLOCK;   // 256

  float* sse = (float*)d_ws;
  unsigned* cnt = (unsigned*)((char*)d_ws + 64);

  hipMemsetAsync(d_ws, 0, 128, stream);  // zero sse + counter
  vq_fused<<<dim3(nblocks), dim3(512), 0, stream>>>(x, cb, out, sse, cnt, nblocks);
}

// Round 8
// 131.367 us; speedup vs baseline: 1.2534x; 1.0122x over previous
//
#include <hip/hip_runtime.h>

// VectorQuantizer gfx950 R8: R7 wave shape (512 thr, 64 rows/wave, mi=4) but
// HALF-codebook LDS (512 codes, 76 KB) staged twice -> 2 blocks/CU co-resident
// (4 waves/SIMD), de-phased staging/compute overlap across blocks.
// dist2[n,k] = ||x||^2 - 2 x.e_k + ||e_k||^2 ; argmin invariant to ||x||^2.
// A-frags hold bf16(-2x) (exact pow2 scale); MFMA C init = cc = 0.5+||e_k||^2
// so MFMA output IS s in ~[0.31,0.69] (>0 => IEEE bits order-monotonic).
// key = (bits(s) & ~1023) | code ; argmin = v_min_u32 ; ties -> lowest code.
// Keys merge across the two halves in registers. Epilogue gathers winning rows
// from GLOBAL fp32 cb (L2-resident 256 KB -> exact output rows).
// Loss: SSE_row = ||x||^2_fp32 + (s_win - 0.5); x read exactly once.
// CSTRIDE=72 ushorts (144 B): 16B-aligned ds_read_b128, 2-way-only bank
// aliasing (free, m136). LDS total ~77.9 KB -> 2 blocks/CU.

typedef __attribute__((ext_vector_type(8))) short short8;
typedef __attribute__((ext_vector_type(4))) float f32x4;

#define VQ_D 64
#define CSTRIDE 72
#define ROWS_PER_BLOCK 512

__device__ inline unsigned short f2bf(float f) {
  union { float f; unsigned u; } v; v.f = f;
  unsigned r = v.u + 0x7FFFu + ((v.u >> 16) & 1u);  // RNE
  return (unsigned short)(r >> 16);
}

__global__ __launch_bounds__(512, 4) void vq_fused(
    const float* __restrict__ x, const float* __restrict__ cb,
    float* __restrict__ out, float* __restrict__ sse_out,
    unsigned* __restrict__ counter, int nblocks) {
  __shared__ unsigned short cbs[512 * CSTRIDE];  // 73728 B
  __shared__ float c2s[512];                     // 2048 B
  __shared__ int idxs[ROWS_PER_BLOCK];           // 2048 B
  __shared__ float redbuf[8];

  const int tid = threadIdx.x;   // 0..511
  const int wave = tid >> 6;     // 0..7
  const int lane = tid & 63;
  const int quad = lane >> 4;
  const int col = lane & 15;
  const long blockRow0 = (long)blockIdx.x * ROWS_PER_BLOCK;
  const int waveRow0 = wave * 64;

  // ---- (a) A fragments first (global-only; overlaps other block's phases).
  short8 Af[4][2];
  float xsq = 0.f;
#pragma unroll
  for (int mi = 0; mi < 4; ++mi) {
#pragma unroll
    for (int ks = 0; ks < 2; ++ks) {
      long row = blockRow0 + waveRow0 + mi * 16 + col;
      const f32x4* xp = (const f32x4*)(x + row * VQ_D + ks * 32 + quad * 8);
      f32x4 lo = xp[0];
      f32x4 hi = xp[1];
      xsq += lo[0] * lo[0] + lo[1] * lo[1] + lo[2] * lo[2] + lo[3] * lo[3] +
             hi[0] * hi[0] + hi[1] * hi[1] + hi[2] * hi[2] + hi[3] * hi[3];
      short8 a;
      a[0] = (short)f2bf(-2.f * lo[0]); a[1] = (short)f2bf(-2.f * lo[1]);
      a[2] = (short)f2bf(-2.f * lo[2]); a[3] = (short)f2bf(-2.f * lo[3]);
      a[4] = (short)f2bf(-2.f * hi[0]); a[5] = (short)f2bf(-2.f * hi[1]);
      a[6] = (short)f2bf(-2.f * hi[2]); a[7] = (short)f2bf(-2.f * hi[3]);
      Af[mi][ks] = a;
    }
  }

  unsigned bk[4][4];
#pragma unroll
  for (int mi = 0; mi < 4; ++mi)
#pragma unroll
    for (int r = 0; r < 4; ++r) bk[mi][r] = 0xFFFFFFFFu;

  // ---- (b) Two passes: stage 512 codes -> 32-iter K-loop.
#pragma unroll 1
  for (int half = 0; half < 2; ++half) {
    if (half) __syncthreads();  // prior K-loop LDS reads complete before overwrite

    // Stage: 512 codes x 8 pieces = 4096 chunks / 512 thr = 8 iters.
    const float* src = cb + (size_t)half * 512 * VQ_D;
#pragma unroll
    for (int r = 0; r < 8; ++r) {
      int id = r * 512 + tid;  // code = id>>3, piece = id&7
      int code = id >> 3;
      int piece = id & 7;
      const f32x4* sp = (const f32x4*)(src + (size_t)code * VQ_D + piece * 8);
      f32x4 lo = sp[0];
      f32x4 hi = sp[1];
      short8 v;
      v[0] = (short)f2bf(lo[0]); v[1] = (short)f2bf(lo[1]);
      v[2] = (short)f2bf(lo[2]); v[3] = (short)f2bf(lo[3]);
      v[4] = (short)f2bf(hi[0]); v[5] = (short)f2bf(hi[1]);
      v[6] = (short)f2bf(hi[2]); v[7] = (short)f2bf(hi[3]);
      *(short8*)(cbs + code * CSTRIDE + piece * 8) = v;
      float p = lo[0] * lo[0] + lo[1] * lo[1] + lo[2] * lo[2] + lo[3] * lo[3] +
                hi[0] * hi[0] + hi[1] * hi[1] + hi[2] * hi[2] + hi[3] * hi[3];
      p += __shfl_xor(p, 1);
      p += __shfl_xor(p, 2);
      p += __shfl_xor(p, 4);
      if (piece == 0) c2s[code] = p + 0.5f;
    }
    __syncthreads();

    // K-loop: 32 iters x 16 codes.
    const unsigned short* bbase = cbs + (size_t)col * CSTRIDE + quad * 8;
    const unsigned cbase = (unsigned)(half << 9) | (unsigned)col;
#pragma unroll 4
    for (int t = 0; t < 32; ++t) {
      const unsigned short* bp = bbase + t * 16 * CSTRIDE;
      short8 b0 = *(const short8*)bp;
      short8 b1 = *(const short8*)(bp + 32);
      float cc = c2s[t * 16 + col];

      f32x4 acc[4];
#pragma unroll
      for (int mi = 0; mi < 4; ++mi) {
        f32x4 a = {cc, cc, cc, cc};
        a = __builtin_amdgcn_mfma_f32_16x16x32_bf16(Af[mi][0], b0, a, 0, 0, 0);
        a = __builtin_amdgcn_mfma_f32_16x16x32_bf16(Af[mi][1], b1, a, 0, 0, 0);
        acc[mi] = a;
      }

      const unsigned code = cbase | (unsigned)(t << 4);
#pragma unroll
      for (int mi = 0; mi < 4; ++mi)
#pragma unroll
        for (int r = 0; r < 4; ++r)
          bk[mi][r] = min(bk[mi][r], (__float_as_uint(acc[mi][r]) & 0xFFFFFC00u) | code);
    }
  }

  // ---- (c) Col-reduce keys (all 16 cols end with the row minimum).
#pragma unroll
  for (int off = 1; off < 16; off <<= 1) {
#pragma unroll
    for (int mi = 0; mi < 4; ++mi)
#pragma unroll
      for (int r = 0; r < 4; ++r) {
        unsigned o = (unsigned)__shfl_xor((int)bk[mi][r], off);
        bk[mi][r] = min(bk[mi][r], o);
      }
  }

  // s_win sum for the loss; each row duplicated on 16 cols -> x1/16.
  float ssum = 0.f;
#pragma unroll
  for (int mi = 0; mi < 4; ++mi)
#pragma unroll
    for (int r = 0; r < 4; ++r)
      ssum += __uint_as_float(bk[mi][r] & 0xFFFFFC00u) - 0.5f;

  // Per-wave idxs (same-wave LDS write->read; no block barrier needed).
  if (col == 0) {
#pragma unroll
    for (int mi = 0; mi < 4; ++mi)
#pragma unroll
      for (int r = 0; r < 4; ++r)
        idxs[waveRow0 + mi * 16 + quad * 4 + r] = (int)(bk[mi][r] & 1023u);
  }

  // ---- (d) Epilogue: gather winners from GLOBAL fp32 cb (L2-hot), write out.
  const f32x4* cb4 = (const f32x4*)cb;
  f32x4* out4 = (f32x4*)out;
#pragma unroll
  for (int i = 0; i < 16; ++i) {
    int c = i * 64 + lane;   // 0..1023 : row_l = c>>4 (0..63), d4 = c&15
    int row_l = c >> 4;
    int d4 = c & 15;
    int idx = idxs[waveRow0 + row_l];
    f32x4 cv = cb4[(size_t)idx * 16 + d4];
    long gi = (blockRow0 + waveRow0 + row_l) * 16 + d4;
    out4[gi] = cv;
  }

  // ---- (e) Loss: SSE = sum_rows ||x||^2 + sum_rows (s_win - 0.5).
  float part = xsq + ssum * 0.0625f;
#pragma unroll
  for (int off = 32; off; off >>= 1) part += __shfl_down(part, off);
  if (lane == 0) redbuf[wave] = part;
  __syncthreads();
  if (tid == 0) {
    float s = 0.f;
#pragma unroll
    for (int w = 0; w < 8; ++w) s += redbuf[w];
    atomicAdd(sse_out, s);
    __threadfence();
    unsigned old = atomicAdd(counter, 1u);
    if (old == (unsigned)(nblocks - 1)) {
      float tot = atomicAdd(sse_out, 0.f);
      long nelem = (long)nblocks * ROWS_PER_BLOCK * VQ_D;
      out[nelem] = 1.25f * tot / (float)nelem;
    }
  }
}

extern "C" void kernel_launch(void* const* d_in, const int* in_sizes, int n_in,
                              void* d_out, int out_size, void* d_ws, size_t ws_size,
                              hipStream_t stream) {
  const float* x = (const float*)d_in[0];
  const float* cb = (const float*)d_in[1];
  float* out = (float*)d_out;

  const long n_elem = (long)in_sizes[0];        // 8388608
  const int nrows = (int)(n_elem / VQ_D);       // 131072
  const int nblocks = nrows / ROWS_PER_BLOCK;   // 256

  float* sse = (float*)d_ws;
  unsigned* cnt = (unsigned*)((char*)d_ws + 64);

  hipMemsetAsync(d_ws, 0, 128, stream);  // zero sse + counter
  vq_fused<<<dim3(nblocks), dim3(512), 0, stream>>>(x, cb, out, sse, cnt, nblocks);
}